// Round 8
// baseline (149.351 us; speedup 1.0000x reference)
//
#include <hip/hip_runtime.h>

// GSHashEncoding R8: R7 pipeline + barrier WITHOUT store drain.
// R7's residual: __syncthreads() makes hipcc emit s_waitcnt vmcnt(0) before
// s_barrier -> drains the tile's 16 nt stores every iteration. Correctness
// only needs lgkmcnt(0) (LDS visibility). Use raw s_barrier + manual
// lgkmcnt(0) (HK pattern) so stores and gathers stay in flight across tiles.
//   k1: codes fp32 -> bf16 table in ws (2.62 MB, L2-resident).
//   k2: per-iter: issue maps(i+2) -> issue gathers(i+1) -> consume(i)
//       -> wait(gathers)+LDSWRITE(i+1) -> lgkm-only barrier.

#define RESO    2097152
#define OUT_DIM 48
#define LVL0    65536
#define NCODES  327680
#define BLK     192                    // 3 waves; 192 % 12 == 0
#define TILE    256
#define NITER   16                     // TILE / (BLK/12)
#define TPB     4                      // tiles per block
#define NBLK    (RESO / (TILE * TPB))  // 2048

typedef int            vi4 __attribute__((ext_vector_type(4)));
typedef float          vf4 __attribute__((ext_vector_type(4)));
typedef unsigned short vu4 __attribute__((ext_vector_type(4)));

static __device__ __forceinline__ unsigned short f2bf_rne(float x) {
    unsigned int u = __float_as_uint(x);
    u += 0x7fffu + ((u >> 16) & 1u);
    return (unsigned short)(u >> 16);
}
static __device__ __forceinline__ float bf2f(unsigned short h) {
    return __uint_as_float(((unsigned int)h) << 16);
}

// Barrier that waits only on LDS ops (no vmcnt(0) store drain).
static __device__ __forceinline__ void barrier_lds_only() {
    __builtin_amdgcn_sched_barrier(0);
    asm volatile("s_waitcnt lgkmcnt(0)" ::: "memory");
    __builtin_amdgcn_s_barrier();
    __builtin_amdgcn_sched_barrier(0);
}

// ---- k1: codes fp32 -> bf16 table ----
__global__ __launch_bounds__(256) void convert_kernel(
    const float* __restrict__ codes, unsigned short* __restrict__ bf)
{
    const int i = blockIdx.x * 256 + threadIdx.x;
    const vf4 v = ((const vf4*)codes)[i];
    vu4 o;
    o.x = f2bf_rne(v.x); o.y = f2bf_rne(v.y);
    o.z = f2bf_rne(v.z); o.w = f2bf_rne(v.w);
    ((vu4*)bf)[i] = o;
}

// ---- k2: pipelined fused kernel ----
__global__ __launch_bounds__(BLK) void gshash_pipe_kernel(
    const unsigned short* __restrict__ tab,
    const float* __restrict__ W,
    const vi4*   __restrict__ map0,
    const vi4*   __restrict__ map1,
    float*       __restrict__ out)
{
    __shared__ float feats[2][TILE * 8];   // 16 KB double buffer

    const int t     = threadIdx.x;
    const int col4  = t % 12;
    const int rbase = t / 12;

    vf4 Wv[8];
    #pragma unroll
    for (int k = 0; k < 8; ++k)
        Wv[k] = ((const vf4*)(W + k * OUT_DIM))[col4];

    const unsigned short* __restrict__ t1 = tab + LVL0 * 4;
    const size_t row00 = (size_t)blockIdx.x * (TPB * TILE);

    vi4 m0b[2], m1b[2], n0b[2], n1b[2];    // double-buffered map regs
    unsigned short g[16];                  // in-flight gathered bf16 (raw)

    #define LOADMAPS(j, s) {                                                  \
        const size_t r0 = row00 + (size_t)(j) * TILE;                         \
        m0b[s] = __builtin_nontemporal_load(&map0[r0 + t]);                   \
        m1b[s] = __builtin_nontemporal_load(&map1[r0 + t]);                   \
        if (t < TILE - BLK) {                                                 \
            n0b[s] = __builtin_nontemporal_load(&map0[r0 + BLK + t]);         \
            n1b[s] = __builtin_nontemporal_load(&map1[r0 + BLK + t]);         \
        } }

    #define GATHERS(s) {                                                      \
        g[0] = tab[m0b[s].x * 4 + 0];                                         \
        g[1] = tab[m0b[s].y * 4 + 1];                                         \
        g[2] = tab[m0b[s].z * 4 + 2];                                         \
        g[3] = tab[m0b[s].w * 4 + 3];                                         \
        g[4] = t1[m1b[s].x * 4 + 0];                                          \
        g[5] = t1[m1b[s].y * 4 + 1];                                          \
        g[6] = t1[m1b[s].z * 4 + 2];                                          \
        g[7] = t1[m1b[s].w * 4 + 3];                                          \
        if (t < TILE - BLK) {                                                 \
            g[8]  = tab[n0b[s].x * 4 + 0];                                    \
            g[9]  = tab[n0b[s].y * 4 + 1];                                    \
            g[10] = tab[n0b[s].z * 4 + 2];                                    \
            g[11] = tab[n0b[s].w * 4 + 3];                                    \
            g[12] = t1[n1b[s].x * 4 + 0];                                     \
            g[13] = t1[n1b[s].y * 4 + 1];                                     \
            g[14] = t1[n1b[s].z * 4 + 2];                                     \
            g[15] = t1[n1b[s].w * 4 + 3];                                     \
        } }

    #define LDSWRITE(buf) {                                                   \
        vf4 a, b;                                                             \
        a.x = bf2f(g[0]); a.y = bf2f(g[1]); a.z = bf2f(g[2]); a.w = bf2f(g[3]); \
        b.x = bf2f(g[4]); b.y = bf2f(g[5]); b.z = bf2f(g[6]); b.w = bf2f(g[7]); \
        *(vf4*)&feats[buf][t * 8]     = a;                                    \
        *(vf4*)&feats[buf][t * 8 + 4] = b;                                    \
        if (t < TILE - BLK) {                                                 \
            vf4 c, d;                                                         \
            c.x = bf2f(g[8]);  c.y = bf2f(g[9]);  c.z = bf2f(g[10]); c.w = bf2f(g[11]); \
            d.x = bf2f(g[12]); d.y = bf2f(g[13]); d.z = bf2f(g[14]); d.w = bf2f(g[15]); \
            *(vf4*)&feats[buf][(BLK + t) * 8]     = c;                        \
            *(vf4*)&feats[buf][(BLK + t) * 8 + 4] = d;                        \
        } }

    // prolog: tiles 0,1 maps; tile 0 gathers -> LDS[0]
    LOADMAPS(0, 0);
    LOADMAPS(1, 1);
    GATHERS(0);
    LDSWRITE(0);
    barrier_lds_only();

    #pragma unroll
    for (int i = 0; i < TPB; ++i) {
        const int cur = i & 1;

        if (i + 2 < TPB) LOADMAPS(i + 2, cur);       // slot cur free after GATHERS below
        if (i + 1 < TPB) GATHERS(cur ^ 1);           // issue; waited at LDSWRITE

        // consume tile i (gather latency hides under these 16 stores)
        vf4* __restrict__ out4 = (vf4*)(out + (row00 + (size_t)i * TILE) * OUT_DIM);
        #pragma unroll
        for (int j = 0; j < NITER; ++j) {
            const int r = j * 16 + rbase;
            const vf4 fa = *(const vf4*)&feats[cur][r * 8];
            const vf4 fb = *(const vf4*)&feats[cur][r * 8 + 4];
            vf4 acc = fa.x * Wv[0];
            acc += fa.y * Wv[1];
            acc += fa.z * Wv[2];
            acc += fa.w * Wv[3];
            acc += fb.x * Wv[4];
            acc += fb.y * Wv[5];
            acc += fb.z * Wv[6];
            acc += fb.w * Wv[7];
            __builtin_nontemporal_store(acc, &out4[j * BLK + t]);
        }

        if (i + 1 < TPB) {
            LDSWRITE(cur ^ 1);             // compiler waits vmcnt(<=stores) for g[]
            barrier_lds_only();            // no store drain
        }
    }
    #undef LOADMAPS
    #undef GATHERS
    #undef LDSWRITE
}

// ---- fallback: fused fp32 single-tile kernel (if ws too small) ----
__global__ __launch_bounds__(BLK) void gshash_f32_kernel(
    const float* __restrict__ codes,
    const float* __restrict__ W,
    const vi4*   __restrict__ map0,
    const vi4*   __restrict__ map1,
    float*       __restrict__ out)
{
    __shared__ float feats[TILE * 8];
    const int t     = threadIdx.x;
    const int col4  = t % 12;
    const int rbase = t / 12;
    const size_t row0 = (size_t)blockIdx.x * TILE;

    vf4 Wv[8];
    #pragma unroll
    for (int k = 0; k < 8; ++k)
        Wv[k] = ((const vf4*)(W + k * OUT_DIM))[col4];

    const float* __restrict__ c1 = codes + LVL0 * 4;
    #pragma unroll
    for (int half = 0; half < 2; ++half) {
        const int r = half * BLK + t;
        if (half == 0 || t < TILE - BLK) {
            const vi4 m0 = __builtin_nontemporal_load(&map0[row0 + r]);
            const vi4 m1 = __builtin_nontemporal_load(&map1[row0 + r]);
            vf4 a, b;
            a.x = codes[m0.x * 4 + 0];
            a.y = codes[m0.y * 4 + 1];
            a.z = codes[m0.z * 4 + 2];
            a.w = codes[m0.w * 4 + 3];
            b.x = c1[m1.x * 4 + 0];
            b.y = c1[m1.y * 4 + 1];
            b.z = c1[m1.z * 4 + 2];
            b.w = c1[m1.w * 4 + 3];
            *(vf4*)&feats[r * 8]     = a;
            *(vf4*)&feats[r * 8 + 4] = b;
        }
    }
    __syncthreads();

    vf4* __restrict__ out4 = (vf4*)(out + row0 * OUT_DIM);
    #pragma unroll
    for (int j = 0; j < NITER; ++j) {
        const int r = j * 16 + rbase;
        const vf4 fa = *(const vf4*)&feats[r * 8];
        const vf4 fb = *(const vf4*)&feats[r * 8 + 4];
        vf4 acc = fa.x * Wv[0];
        acc += fa.y * Wv[1];
        acc += fa.z * Wv[2];
        acc += fa.w * Wv[3];
        acc += fb.x * Wv[4];
        acc += fb.y * Wv[5];
        acc += fb.z * Wv[6];
        acc += fb.w * Wv[7];
        __builtin_nontemporal_store(acc, &out4[j * BLK + t]);
    }
}

extern "C" void kernel_launch(void* const* d_in, const int* in_sizes, int n_in,
                              void* d_out, int out_size, void* d_ws, size_t ws_size,
                              hipStream_t stream) {
    const float* codes = (const float*)d_in[0];
    const float* W     = (const float*)d_in[1];
    const vi4*   map0  = (const vi4*)d_in[2];
    const vi4*   map1  = (const vi4*)d_in[3];
    float*       out   = (float*)d_out;

    const size_t tab_bytes = (size_t)NCODES * 4 * sizeof(unsigned short); // 2.62 MB

    if (ws_size >= tab_bytes) {
        unsigned short* tab = (unsigned short*)d_ws;
        convert_kernel<<<NCODES / 256, 256, 0, stream>>>(codes, tab);
        gshash_pipe_kernel<<<NBLK, BLK, 0, stream>>>(tab, W, map0, map1, out);
    } else {
        gshash_f32_kernel<<<RESO / TILE, BLK, 0, stream>>>(codes, W, map0, map1, out);
    }
}

// Round 9
// 140.830 us; speedup vs baseline: 1.0605x; 1.0605x over previous
//
#include <hip/hip_runtime.h>

// GSHashEncoding R9: deeper pipeline. R8 showed store-drain wasn't the gap.
// New model: gather is MSHR-latency bound (~94us, 0.28 lines/cy/CU); residual
// 45us = prolog exposure (TPB=4 -> 1/5 of block life) + only one consume
// phase of slack between gather-issue and gather-wait.
// Fix: TPB=8 (prolog 1/9, NBLK=1024 = 4 blocks/CU) + depth-2 gather pipeline
// (gathers issued 2 tiles ahead into 2 reg buffers; maps triple-buffered).
//   k1: codes fp32 -> bf16 table in ws (2.62 MB, L2-resident).

#define RESO    2097152
#define OUT_DIM 48
#define LVL0    65536
#define NCODES  327680
#define BLK     192                    // 3 waves; 192 % 12 == 0
#define TILE    256
#define NITER   16                     // TILE / (BLK/12)
#define TPB     8                      // tiles per block
#define NBLK    (RESO / (TILE * TPB))  // 1024

typedef int            vi4 __attribute__((ext_vector_type(4)));
typedef float          vf4 __attribute__((ext_vector_type(4)));
typedef unsigned short vu4 __attribute__((ext_vector_type(4)));

static __device__ __forceinline__ unsigned short f2bf_rne(float x) {
    unsigned int u = __float_as_uint(x);
    u += 0x7fffu + ((u >> 16) & 1u);
    return (unsigned short)(u >> 16);
}
static __device__ __forceinline__ float bf2f(unsigned short h) {
    return __uint_as_float(((unsigned int)h) << 16);
}

// Barrier that waits only on LDS ops (no vmcnt(0) store/gather drain).
static __device__ __forceinline__ void barrier_lds_only() {
    __builtin_amdgcn_sched_barrier(0);
    asm volatile("s_waitcnt lgkmcnt(0)" ::: "memory");
    __builtin_amdgcn_s_barrier();
    __builtin_amdgcn_sched_barrier(0);
}

// ---- k1: codes fp32 -> bf16 table ----
__global__ __launch_bounds__(256) void convert_kernel(
    const float* __restrict__ codes, unsigned short* __restrict__ bf)
{
    const int i = blockIdx.x * 256 + threadIdx.x;
    const vf4 v = ((const vf4*)codes)[i];
    vu4 o;
    o.x = f2bf_rne(v.x); o.y = f2bf_rne(v.y);
    o.z = f2bf_rne(v.z); o.w = f2bf_rne(v.w);
    ((vu4*)bf)[i] = o;
}

// ---- k2: depth-2 pipelined fused kernel ----
__global__ __launch_bounds__(BLK) void gshash_pipe_kernel(
    const unsigned short* __restrict__ tab,
    const float* __restrict__ W,
    const vi4*   __restrict__ map0,
    const vi4*   __restrict__ map1,
    float*       __restrict__ out)
{
    __shared__ float feats[2][TILE * 8];   // 16 KB double buffer

    const int t     = threadIdx.x;
    const int col4  = t % 12;
    const int rbase = t / 12;

    vf4 Wv[8];
    #pragma unroll
    for (int k = 0; k < 8; ++k)
        Wv[k] = ((const vf4*)(W + k * OUT_DIM))[col4];

    const unsigned short* __restrict__ t1 = tab + LVL0 * 4;
    const size_t row00 = (size_t)blockIdx.x * (TPB * TILE);

    vi4 m0b[3], m1b[3], n0b[3], n1b[3];    // triple-buffered map regs
    unsigned short gA[16], gB[16];         // depth-2 in-flight gather buffers

    #define LOADMAPS(j, s) {                                                  \
        const size_t r0 = row00 + (size_t)(j) * TILE;                         \
        m0b[s] = __builtin_nontemporal_load(&map0[r0 + t]);                   \
        m1b[s] = __builtin_nontemporal_load(&map1[r0 + t]);                   \
        if (t < TILE - BLK) {                                                 \
            n0b[s] = __builtin_nontemporal_load(&map0[r0 + BLK + t]);         \
            n1b[s] = __builtin_nontemporal_load(&map1[r0 + BLK + t]);         \
        } }

    #define GATHERS(s, G) {                                                   \
        G[0] = tab[m0b[s].x * 4 + 0];                                         \
        G[1] = tab[m0b[s].y * 4 + 1];                                         \
        G[2] = tab[m0b[s].z * 4 + 2];                                         \
        G[3] = tab[m0b[s].w * 4 + 3];                                         \
        G[4] = t1[m1b[s].x * 4 + 0];                                          \
        G[5] = t1[m1b[s].y * 4 + 1];                                          \
        G[6] = t1[m1b[s].z * 4 + 2];                                          \
        G[7] = t1[m1b[s].w * 4 + 3];                                          \
        if (t < TILE - BLK) {                                                 \
            G[8]  = tab[n0b[s].x * 4 + 0];                                    \
            G[9]  = tab[n0b[s].y * 4 + 1];                                    \
            G[10] = tab[n0b[s].z * 4 + 2];                                    \
            G[11] = tab[n0b[s].w * 4 + 3];                                    \
            G[12] = t1[n1b[s].x * 4 + 0];                                     \
            G[13] = t1[n1b[s].y * 4 + 1];                                     \
            G[14] = t1[n1b[s].z * 4 + 2];                                     \
            G[15] = t1[n1b[s].w * 4 + 3];                                     \
        } }

    #define LDSWRITE(G, buf) {                                                \
        vf4 a, b;                                                             \
        a.x = bf2f(G[0]); a.y = bf2f(G[1]); a.z = bf2f(G[2]); a.w = bf2f(G[3]); \
        b.x = bf2f(G[4]); b.y = bf2f(G[5]); b.z = bf2f(G[6]); b.w = bf2f(G[7]); \
        *(vf4*)&feats[buf][t * 8]     = a;                                    \
        *(vf4*)&feats[buf][t * 8 + 4] = b;                                    \
        if (t < TILE - BLK) {                                                 \
            vf4 c, d;                                                         \
            c.x = bf2f(G[8]);  c.y = bf2f(G[9]);  c.z = bf2f(G[10]); c.w = bf2f(G[11]); \
            d.x = bf2f(G[12]); d.y = bf2f(G[13]); d.z = bf2f(G[14]); d.w = bf2f(G[15]); \
            *(vf4*)&feats[buf][(BLK + t) * 8]     = c;                        \
            *(vf4*)&feats[buf][(BLK + t) * 8 + 4] = d;                        \
        } }

    // prolog: maps for tiles 0,1,2; gather tile0 -> LDS[0]; issue tile1 gathers
    LOADMAPS(0, 0);
    LOADMAPS(1, 1);
    LOADMAPS(2, 2);
    GATHERS(0, gA);                    // tile 0 (even -> gA)
    LDSWRITE(gA, 0);                   // exposed once per block
    GATHERS(1, gB);                    // tile 1 (odd -> gB); waited next iter
    barrier_lds_only();

    #pragma unroll
    for (int i = 0; i < TPB; ++i) {
        const int cur = i & 1;

        if (i + 3 < TPB) LOADMAPS(i + 3, (i + 3) % 3);
        if (i + 2 < TPB) {                       // issue gathers 2 tiles ahead
            if (((i + 2) & 1) == 0) { GATHERS((i + 2) % 3, gA); }
            else                    { GATHERS((i + 2) % 3, gB); }
        }

        // consume tile i
        vf4* __restrict__ out4 = (vf4*)(out + (row00 + (size_t)i * TILE) * OUT_DIM);
        #pragma unroll
        for (int j = 0; j < NITER; ++j) {
            const int r = j * 16 + rbase;
            const vf4 fa = *(const vf4*)&feats[cur][r * 8];
            const vf4 fb = *(const vf4*)&feats[cur][r * 8 + 4];
            vf4 acc = fa.x * Wv[0];
            acc += fa.y * Wv[1];
            acc += fa.z * Wv[2];
            acc += fa.w * Wv[3];
            acc += fb.x * Wv[4];
            acc += fb.y * Wv[5];
            acc += fb.z * Wv[6];
            acc += fb.w * Wv[7];
            __builtin_nontemporal_store(acc, &out4[j * BLK + t]);
        }

        if (i + 1 < TPB) {                       // gathers had 2 consume phases of slack
            if (((i + 1) & 1) == 0) { LDSWRITE(gA, 0); }
            else                    { LDSWRITE(gB, 1); }
            barrier_lds_only();
        }
    }
    #undef LOADMAPS
    #undef GATHERS
    #undef LDSWRITE
}

// ---- fallback: fused fp32 single-tile kernel (if ws too small) ----
__global__ __launch_bounds__(BLK) void gshash_f32_kernel(
    const float* __restrict__ codes,
    const float* __restrict__ W,
    const vi4*   __restrict__ map0,
    const vi4*   __restrict__ map1,
    float*       __restrict__ out)
{
    __shared__ float feats[TILE * 8];
    const int t     = threadIdx.x;
    const int col4  = t % 12;
    const int rbase = t / 12;
    const size_t row0 = (size_t)blockIdx.x * TILE;

    vf4 Wv[8];
    #pragma unroll
    for (int k = 0; k < 8; ++k)
        Wv[k] = ((const vf4*)(W + k * OUT_DIM))[col4];

    const float* __restrict__ c1 = codes + LVL0 * 4;
    #pragma unroll
    for (int half = 0; half < 2; ++half) {
        const int r = half * BLK + t;
        if (half == 0 || t < TILE - BLK) {
            const vi4 m0 = __builtin_nontemporal_load(&map0[row0 + r]);
            const vi4 m1 = __builtin_nontemporal_load(&map1[row0 + r]);
            vf4 a, b;
            a.x = codes[m0.x * 4 + 0];
            a.y = codes[m0.y * 4 + 1];
            a.z = codes[m0.z * 4 + 2];
            a.w = codes[m0.w * 4 + 3];
            b.x = c1[m1.x * 4 + 0];
            b.y = c1[m1.y * 4 + 1];
            b.z = c1[m1.z * 4 + 2];
            b.w = c1[m1.w * 4 + 3];
            *(vf4*)&feats[r * 8]     = a;
            *(vf4*)&feats[r * 8 + 4] = b;
        }
    }
    __syncthreads();

    vf4* __restrict__ out4 = (vf4*)(out + row0 * OUT_DIM);
    #pragma unroll
    for (int j = 0; j < NITER; ++j) {
        const int r = j * 16 + rbase;
        const vf4 fa = *(const vf4*)&feats[r * 8];
        const vf4 fb = *(const vf4*)&feats[r * 8 + 4];
        vf4 acc = fa.x * Wv[0];
        acc += fa.y * Wv[1];
        acc += fa.z * Wv[2];
        acc += fa.w * Wv[3];
        acc += fb.x * Wv[4];
        acc += fb.y * Wv[5];
        acc += fb.z * Wv[6];
        acc += fb.w * Wv[7];
        __builtin_nontemporal_store(acc, &out4[j * BLK + t]);
    }
}

extern "C" void kernel_launch(void* const* d_in, const int* in_sizes, int n_in,
                              void* d_out, int out_size, void* d_ws, size_t ws_size,
                              hipStream_t stream) {
    const float* codes = (const float*)d_in[0];
    const float* W     = (const float*)d_in[1];
    const vi4*   map0  = (const vi4*)d_in[2];
    const vi4*   map1  = (const vi4*)d_in[3];
    float*       out   = (float*)d_out;

    const size_t tab_bytes = (size_t)NCODES * 4 * sizeof(unsigned short); // 2.62 MB

    if (ws_size >= tab_bytes) {
        unsigned short* tab = (unsigned short*)d_ws;
        convert_kernel<<<NCODES / 256, 256, 0, stream>>>(codes, tab);
        gshash_pipe_kernel<<<NBLK, BLK, 0, stream>>>(tab, W, map0, map1, out);
    } else {
        gshash_f32_kernel<<<RESO / TILE, BLK, 0, stream>>>(codes, W, map0, map1, out);
    }
}